// Round 1
// baseline (316.253 us; speedup 1.0000x reference)
//
#include <hip/hip_runtime.h>
#include <hip/hip_bf16.h>
#include <math.h>

#define FFT_N 512
#define LOG2N 9

// One block (256 threads) per row of 512 samples.
// Radix-2 DIT Cooley-Tukey in LDS: bit-reverse load, 9 stages, write Re().
__global__ __launch_bounds__(256) void fft512_real_kernel(
        const float* __restrict__ x,
        const float* __restrict__ win,
        float* __restrict__ out) {
    __shared__ float re[FFT_N];
    __shared__ float im[FFT_N];

    const int row = blockIdx.x;
    const int t   = threadIdx.x;
    const float* __restrict__ xr = x + (size_t)row * FFT_N;
    float* __restrict__ orow     = out + (size_t)row * FFT_N;

    // Load 2 elements per thread (coalesced), window, bit-reverse scatter to LDS.
#pragma unroll
    for (int i = 0; i < 2; ++i) {
        const int idx = t + i * 256;
        const float v = xr[idx] * win[idx];
        const int r = __brev((unsigned)idx) >> (32 - LOG2N);
        re[r] = v;
        im[r] = 0.0f;
    }
    __syncthreads();

    // 9 radix-2 stages; 256 butterflies per stage == 1 per thread.
#pragma unroll
    for (int s = 1; s <= LOG2N; ++s) {
        const int m  = 1 << s;
        const int m2 = m >> 1;
        const int j   = t & (m2 - 1);
        const int grp = t >> (s - 1);
        const int i1  = (grp << s) + j;
        const int i2  = i1 + m2;

        // twiddle: exp(-2*pi*i * j / m)
        const float ang = -6.28318530717958647692f * (float)j / (float)m;
        float sn, cs;
        __sincosf(ang, &sn, &cs);

        const float ur = re[i1], ui = im[i1];
        const float vr = re[i2], vi = im[i2];
        const float tr = vr * cs - vi * sn;
        const float ti = vr * sn + vi * cs;
        re[i1] = ur + tr; im[i1] = ui + ti;
        re[i2] = ur - tr; im[i2] = ui - ti;
        __syncthreads();
    }

    // Real part only, coalesced store.
    orow[t]       = re[t];
    orow[t + 256] = re[t + 256];
}

extern "C" void kernel_launch(void* const* d_in, const int* in_sizes, int n_in,
                              void* d_out, int out_size, void* d_ws, size_t ws_size,
                              hipStream_t stream) {
    const float* x   = (const float*)d_in[0];
    const float* win = (const float*)d_in[1];
    float* out       = (float*)d_out;

    const int rows = in_sizes[0] / FFT_N;  // 256*256 = 65536
    hipLaunchKernelGGL(fft512_real_kernel, dim3(rows), dim3(256), 0, stream,
                       x, win, out);
}

// Round 2
// 228.275 us; speedup vs baseline: 1.3854x; 1.3854x over previous
//
#include <hip/hip_runtime.h>
#include <math.h>

#define FFT_N 512
#define ROWS_PER_BLOCK 4
#define LDS_STRIDE 576   // padded per-wave region (floats); max addr used = 574

// In-register 8-point complex DFT (DIF radix-2^3), outputs in NATURAL order.
// Forward convention: X[k] = sum_n x[n] e^{-2*pi*i*n*k/8}
__device__ __forceinline__ void fft8(float* re, float* im) {
    const float C = 0.70710678118654752440f;
    float tr[8], ti[8];
    tr[0]=re[0]+re[4]; ti[0]=im[0]+im[4];
    tr[4]=re[0]-re[4]; ti[4]=im[0]-im[4];
    tr[1]=re[1]+re[5]; ti[1]=im[1]+im[5];
    tr[5]=re[1]-re[5]; ti[5]=im[1]-im[5];
    tr[2]=re[2]+re[6]; ti[2]=im[2]+im[6];
    tr[6]=re[2]-re[6]; ti[6]=im[2]-im[6];
    tr[3]=re[3]+re[7]; ti[3]=im[3]+im[7];
    tr[7]=re[3]-re[7]; ti[7]=im[3]-im[7];
    // twiddles: t5 *= w8^1 = c - ci ; t6 *= w8^2 = -i ; t7 *= w8^3 = -c - ci
    { float a=tr[5], b=ti[5]; tr[5]=C*(a+b); ti[5]=C*(b-a); }
    { float a=tr[6], b=ti[6]; tr[6]=b;       ti[6]=-a;      }
    { float a=tr[7], b=ti[7]; tr[7]=C*(b-a); ti[7]=-C*(a+b);}
    // DFT4 on evens -> X0,X2,X4,X6
    {
        float s0r=tr[0]+tr[2], s0i=ti[0]+ti[2];
        float s2r=tr[0]-tr[2], s2i=ti[0]-ti[2];
        float s1r=tr[1]+tr[3], s1i=ti[1]+ti[3];
        float dr =tr[1]-tr[3], di =ti[1]-ti[3];
        float s3r= di, s3i=-dr;                 // -i*(u1-u3)
        re[0]=s0r+s1r; im[0]=s0i+s1i;
        re[2]=s2r+s3r; im[2]=s2i+s3i;
        re[4]=s0r-s1r; im[4]=s0i-s1i;
        re[6]=s2r-s3r; im[6]=s2i-s3i;
    }
    // DFT4 on odds -> X1,X3,X5,X7
    {
        float s0r=tr[4]+tr[6], s0i=ti[4]+ti[6];
        float s2r=tr[4]-tr[6], s2i=ti[4]-ti[6];
        float s1r=tr[5]+tr[7], s1i=ti[5]+ti[7];
        float dr =tr[5]-tr[7], di =ti[5]-ti[7];
        float s3r= di, s3i=-dr;
        re[1]=s0r+s1r; im[1]=s0i+s1i;
        re[3]=s2r+s3r; im[3]=s2i+s3i;
        re[5]=s0r-s1r; im[5]=s0i-s1i;
        re[7]=s2r-s3r; im[7]=s2i-s3i;
    }
}

// One wave (64 lanes) per 512-point row; 4 rows per block.
// Decimation: n = 64*n1 + 8*n2 + n3 ; k = k1 + 8*k2 + 64*k3 (digits 0..7).
// Stage A: DFT8 over n1 (regs) + twiddle W512^{t*k1}, t = lane.
// Stage B: DFT8 over n2 (regs) + twiddle W64^{n3*k2}, after LDS transpose 1.
// Stage C: DFT8 over n3 (regs), after LDS transpose 2; coalesced store of Re.
__global__ __launch_bounds__(256) void fft512_r8_kernel(
        const float* __restrict__ x,
        const float* __restrict__ win,
        float* __restrict__ out) {
    __shared__ float lre[ROWS_PER_BLOCK * LDS_STRIDE];
    __shared__ float lim[ROWS_PER_BLOCK * LDS_STRIDE];

    const int wave = threadIdx.x >> 6;
    const int lane = threadIdx.x & 63;
    const int row  = blockIdx.x * ROWS_PER_BLOCK + wave;
    float* __restrict__ Lre = lre + wave * LDS_STRIDE;
    float* __restrict__ Lim = lim + wave * LDS_STRIDE;

    const float* __restrict__ xr = x + (size_t)row * FFT_N;
    float re[8], im[8];

    // Coalesced load (64 consecutive floats per wave per n1), window, imag=0.
#pragma unroll
    for (int n1 = 0; n1 < 8; ++n1) {
        re[n1] = xr[lane + 64 * n1] * win[lane + 64 * n1];
        im[n1] = 0.0f;
    }

    // ---- Stage A ----
    fft8(re, im);
#pragma unroll
    for (int k1 = 1; k1 < 8; ++k1) {
        float s, c;
        __sincosf(-6.283185307179586f * (float)(lane * k1) * (1.0f / 512.0f), &s, &c);
        float a = re[k1], b = im[k1];
        re[k1] = a * c - b * s;
        im[k1] = a * s + b * c;
    }

    // ---- Exchange 1: layout addr = k1*72 + t  (write 2-way, read 2-way max) ----
#pragma unroll
    for (int k1 = 0; k1 < 8; ++k1) {
        Lre[k1 * 72 + lane] = re[k1];
        Lim[k1 * 72 + lane] = im[k1];
    }
    __syncthreads();
    const int k1p = lane >> 3, n3p = lane & 7;
#pragma unroll
    for (int n2 = 0; n2 < 8; ++n2) {
        re[n2] = Lre[k1p * 72 + n2 * 8 + n3p];
        im[n2] = Lim[k1p * 72 + n2 * 8 + n3p];
    }

    // ---- Stage B ----
    fft8(re, im);
#pragma unroll
    for (int k2 = 1; k2 < 8; ++k2) {
        float s, c;
        __sincosf(-6.283185307179586f * (float)(n3p * k2) * (1.0f / 64.0f), &s, &c);
        float a = re[k2], b = im[k2];
        re[k2] = a * c - b * s;
        im[k2] = a * s + b * c;
    }
    __syncthreads();

    // ---- Exchange 2: layout addr = (k1*8 + k2)*9 + n3  (uniform 2 lanes/bank) ----
#pragma unroll
    for (int k2 = 0; k2 < 8; ++k2) {
        int a = (k1p * 8 + k2) * 9 + n3p;
        Lre[a] = re[k2];
        Lim[a] = im[k2];
    }
    __syncthreads();
    const int k1pp = lane & 7, k2pp = lane >> 3;
#pragma unroll
    for (int n3 = 0; n3 < 8; ++n3) {
        int a = (k1pp * 8 + k2pp) * 9 + n3;
        re[n3] = Lre[a];
        im[n3] = Lim[a];
    }

    // ---- Stage C + coalesced store of real part ----
    fft8(re, im);
    float* __restrict__ orow = out + (size_t)row * FFT_N;
#pragma unroll
    for (int k3 = 0; k3 < 8; ++k3) {
        orow[lane + 64 * k3] = re[k3];
    }
}

extern "C" void kernel_launch(void* const* d_in, const int* in_sizes, int n_in,
                              void* d_out, int out_size, void* d_ws, size_t ws_size,
                              hipStream_t stream) {
    const float* x   = (const float*)d_in[0];
    const float* win = (const float*)d_in[1];
    float* out       = (float*)d_out;

    const int rows   = in_sizes[0] / FFT_N;            // 65536
    const int blocks = rows / ROWS_PER_BLOCK;          // 16384
    hipLaunchKernelGGL(fft512_r8_kernel, dim3(blocks), dim3(256), 0, stream,
                       x, win, out);
}

// Round 3
// 226.628 us; speedup vs baseline: 1.3955x; 1.0073x over previous
//
#include <hip/hip_runtime.h>
#include <math.h>

#define FFT_N 512
#define WAVES_PER_BLOCK 4
#define LDS_STRIDE 576   // per-wave region in float2; max addr used = 574

// Wave-level sync for wave-private LDS exchange: drain LDS pipe + block
// compiler motion. No __syncthreads needed (each wave owns its region).
#define WAVE_LDS_SYNC() do { \
    __builtin_amdgcn_wave_barrier(); \
    asm volatile("s_waitcnt lgkmcnt(0)" ::: "memory"); \
    __builtin_amdgcn_wave_barrier(); \
} while (0)

// In-register 8-point complex DFT (DIF radix-2^3), outputs in NATURAL order.
__device__ __forceinline__ void fft8(float* re, float* im) {
    const float C = 0.70710678118654752440f;
    float tr[8], ti[8];
    tr[0]=re[0]+re[4]; ti[0]=im[0]+im[4];
    tr[4]=re[0]-re[4]; ti[4]=im[0]-im[4];
    tr[1]=re[1]+re[5]; ti[1]=im[1]+im[5];
    tr[5]=re[1]-re[5]; ti[5]=im[1]-im[5];
    tr[2]=re[2]+re[6]; ti[2]=im[2]+im[6];
    tr[6]=re[2]-re[6]; ti[6]=im[2]-im[6];
    tr[3]=re[3]+re[7]; ti[3]=im[3]+im[7];
    tr[7]=re[3]-re[7]; ti[7]=im[3]-im[7];
    { float a=tr[5], b=ti[5]; tr[5]=C*(a+b); ti[5]=C*(b-a); }
    { float a=tr[6], b=ti[6]; tr[6]=b;       ti[6]=-a;      }
    { float a=tr[7], b=ti[7]; tr[7]=C*(b-a); ti[7]=-C*(a+b);}
    {
        float s0r=tr[0]+tr[2], s0i=ti[0]+ti[2];
        float s2r=tr[0]-tr[2], s2i=ti[0]-ti[2];
        float s1r=tr[1]+tr[3], s1i=ti[1]+ti[3];
        float dr =tr[1]-tr[3], di =ti[1]-ti[3];
        float s3r= di, s3i=-dr;
        re[0]=s0r+s1r; im[0]=s0i+s1i;
        re[2]=s2r+s3r; im[2]=s2i+s3i;
        re[4]=s0r-s1r; im[4]=s0i-s1i;
        re[6]=s2r-s3r; im[6]=s2i-s3i;
    }
    {
        float s0r=tr[4]+tr[6], s0i=ti[4]+ti[6];
        float s2r=tr[4]-tr[6], s2i=ti[4]-ti[6];
        float s1r=tr[5]+tr[7], s1i=ti[5]+ti[7];
        float dr =tr[5]-tr[7], di =ti[5]-ti[7];
        float s3r= di, s3i=-dr;
        re[1]=s0r+s1r; im[1]=s0i+s1i;
        re[3]=s2r+s3r; im[3]=s2i+s3i;
        re[5]=s0r-s1r; im[5]=s0i-s1i;
        re[7]=s2r-s3r; im[7]=s2i-s3i;
    }
}

// Apply tw[k] = base^k (chained complex multiply) to regs 1..7.
__device__ __forceinline__ void twiddle_chain(float* re, float* im,
                                              float c, float s) {
    float cr = c, ci = s;
#pragma unroll
    for (int k = 1; k < 8; ++k) {
        float a = re[k], b = im[k];
        re[k] = a * cr - b * ci;
        im[k] = a * ci + b * cr;
        float ncr = cr * c - ci * s;
        float nci = cr * s + ci * c;
        cr = ncr; ci = nci;
    }
}

// One wave per PAIR of rows: z = x[2q] + i*x[2q+1], one 512-pt complex FFT,
// unpack Re(A)= (ReZ[k]+ReZ[N-k])/2, Re(B) = (ImZ[k]+ImZ[N-k])/2.
// Decimation: n = 64*n1 + 8*n2 + n3 ; k = k1 + 8*k2 + 64*k3.
__global__ __launch_bounds__(256) void fft512_pack2_kernel(
        const float* __restrict__ x,
        const float* __restrict__ win,
        float* __restrict__ out) {
    __shared__ float2 lds[WAVES_PER_BLOCK * LDS_STRIDE];

    const int wave = threadIdx.x >> 6;
    const int lane = threadIdx.x & 63;
    const int pair = blockIdx.x * WAVES_PER_BLOCK + wave;
    float2* __restrict__ L = lds + wave * LDS_STRIDE;

    const float* __restrict__ x0 = x + (size_t)(2 * pair) * FFT_N;
    const float* __restrict__ x1 = x0 + FFT_N;

    float re[8], im[8];

    // Coalesced loads; row A -> real, row B -> imag. Window shared.
#pragma unroll
    for (int n1 = 0; n1 < 8; ++n1) {
        const int idx = lane + 64 * n1;
        const float w = win[idx];
        re[n1] = x0[idx] * w;
        im[n1] = x1[idx] * w;
    }

    // ---- Stage A: DFT8 over n1 + twiddle W512^{lane*k1} ----
    fft8(re, im);
    {
        float s, c;
        __sincosf(-6.283185307179586f * (float)lane * (1.0f / 512.0f), &s, &c);
        twiddle_chain(re, im, c, s);
    }

    // ---- Exchange 1: addr = k1*72 + lane ----
#pragma unroll
    for (int k1 = 0; k1 < 8; ++k1)
        L[k1 * 72 + lane] = make_float2(re[k1], im[k1]);
    WAVE_LDS_SYNC();
    const int k1p = lane >> 3, n3p = lane & 7;
#pragma unroll
    for (int n2 = 0; n2 < 8; ++n2) {
        float2 v = L[k1p * 72 + n2 * 8 + n3p];
        re[n2] = v.x; im[n2] = v.y;
    }
    WAVE_LDS_SYNC();

    // ---- Stage B: DFT8 over n2 + twiddle W64^{n3p*k2} ----
    fft8(re, im);
    {
        float s, c;
        __sincosf(-6.283185307179586f * (float)n3p * (1.0f / 64.0f), &s, &c);
        twiddle_chain(re, im, c, s);
    }

    // ---- Exchange 2: addr = (k1*8 + k2)*9 + n3 ----
#pragma unroll
    for (int k2 = 0; k2 < 8; ++k2)
        L[(k1p * 8 + k2) * 9 + n3p] = make_float2(re[k2], im[k2]);
    WAVE_LDS_SYNC();
    const int k1pp = lane & 7, k2pp = lane >> 3;
#pragma unroll
    for (int n3 = 0; n3 < 8; ++n3) {
        float2 v = L[(k1pp * 8 + k2pp) * 9 + n3];
        re[n3] = v.x; im[n3] = v.y;
    }
    WAVE_LDS_SYNC();

    // ---- Stage C ----
    fft8(re, im);
    // Thread now holds Z[k], k = lane + 64*k3 (register index k3).

    // ---- Exchange 3 (unpack): element k stored at (k>>6)*72 + (k&63) ----
#pragma unroll
    for (int k3 = 0; k3 < 8; ++k3)
        L[k3 * 72 + lane] = make_float2(re[k3], im[k3]);
    WAVE_LDS_SYNC();

    float* __restrict__ o0 = out + (size_t)(2 * pair) * FFT_N;
    float* __restrict__ o1 = o0 + FFT_N;
#pragma unroll
    for (int k3 = 0; k3 < 8; ++k3) {
        const int k  = lane + 64 * k3;
        const int kk = (FFT_N - k) & (FFT_N - 1);   // (512 - k) mod 512
        float2 p = L[(kk >> 6) * 72 + (kk & 63)];
        o0[k] = 0.5f * (re[k3] + p.x);
        o1[k] = 0.5f * (im[k3] + p.y);
    }
}

extern "C" void kernel_launch(void* const* d_in, const int* in_sizes, int n_in,
                              void* d_out, int out_size, void* d_ws, size_t ws_size,
                              hipStream_t stream) {
    const float* x   = (const float*)d_in[0];
    const float* win = (const float*)d_in[1];
    float* out       = (float*)d_out;

    const int rows   = in_sizes[0] / FFT_N;              // 65536
    const int pairs  = rows / 2;                         // 32768
    const int blocks = pairs / WAVES_PER_BLOCK;          // 8192
    hipLaunchKernelGGL(fft512_pack2_kernel, dim3(blocks), dim3(256), 0, stream,
                       x, win, out);
}